// Round 18
// baseline (363.825 us; speedup 1.0000x reference)
//
#include <hip/hip_runtime.h>
#include <hip/hip_bf16.h>

typedef __hip_bfloat16 bf16;
typedef __attribute__((ext_vector_type(8))) short short8;
typedef __attribute__((ext_vector_type(4))) float f32x4;

__device__ __forceinline__ float b2f(bf16 v) { return __bfloat162float(v); }
__device__ __forceinline__ bf16 f2b(float v) { return __float2bfloat16(v); }
__device__ __forceinline__ short f2bs(float v) {
    bf16 b = f2b(v);
    return *reinterpret_cast<short*>(&b);
}
__device__ __forceinline__ float bflo(unsigned int u) { return __uint_as_float(u << 16); }
__device__ __forceinline__ float bfhi(unsigned int u) { return __uint_as_float(u & 0xffff0000u); }
__device__ __forceinline__ unsigned int packbf(float lo, float hi) {
    bf16 l = f2b(lo), h = f2b(hi);
    return ((unsigned int)(*(unsigned short*)&h) << 16) | (*(unsigned short*)&l);
}

// DTYPE (resolved rounds 0-9): inputs fp32, output fp32; intermediates bf16.

__global__ void k_sentinel(float* out, int n, float val) {
    int i = blockIdx.x * blockDim.x + threadIdx.x;
    if (i < n) out[i] = val;
}

// ---------------- setup: weight repacks + TyB (blocks 0..168) || edge count (rest) ----------------
#define PREP_BLOCKS 169
__global__ void k_setup(const float* __restrict__ Wl, const float* __restrict__ Wr,
                        const float* __restrict__ Wres, const float* __restrict__ Wp,
                        const float* __restrict__ W1, const float* __restrict__ Et,
                        const float* __restrict__ bp,
                        bf16* __restrict__ WT, bf16* __restrict__ WpT,
                        bf16* __restrict__ W1T, float* __restrict__ TyB,
                        const int* __restrict__ edst, int* __restrict__ counts,
                        int* __restrict__ rank, int e) {
    int b = blockIdx.x;
    if (b < PREP_BLOCKS) {
        int i = b * 256 + threadIdx.x;
        if (i < 36864) {
            int l = i / 12288, rem = i % 12288;
            int col = rem / 64, k = rem % 64;
            int mat = col >> 6, c = col & 63;
            const float* W = (mat == 0) ? Wl : (mat == 1) ? Wr : Wres;
            WT[i] = f2b(W[l * 4096 + k * 64 + c]);
        } else if (i < 40960) {
            int j = i - 36864, col = j / 64, k = j % 64;
            WpT[j] = f2b(Wp[k * 64 + col]);
        } else if (i < 43008) {
            int j = i - 40960, col = j / 64, k = j % 64;
            W1T[j] = f2b(W1[k * 32 + col]);
        } else if (i < 43200) {
            int j = i - 43008, t = j / 64, d = j % 64;
            float s = bp[d];
#pragma unroll
            for (int f = 0; f < 16; ++f) s += Et[t * 16 + f] * Wp[(64 + f) * 64 + d];
            TyB[j] = s;
        }
    } else {
        int i = (b - PREP_BLOCKS) * 256 + threadIdx.x;
        if (i < e) rank[i] = atomicAdd(&counts[edst[i]], 1);
    }
}

// ---------------- encoder + layer-0 xform fused ----------------
__global__ __launch_bounds__(256) void k_encx(
        const float* __restrict__ x, const int* __restrict__ ntype,
        const float* __restrict__ Wt, const float* __restrict__ bt,
        const bf16* __restrict__ WpT, const float* __restrict__ TyB,
        bf16* __restrict__ h0b,
        const bf16* __restrict__ WT0, const float* __restrict__ bl0,
        const float* __restrict__ br0, const float* __restrict__ bc0,
        bf16* __restrict__ xlo, bf16* __restrict__ xro, bf16* __restrict__ reso,
        int n) {
    __shared__ float sWt[512];
    __shared__ float sbt[64];
    __shared__ __align__(16) short sh[4 * 16 * 72];
    int tid = threadIdx.x;
    for (int i = tid; i < 512; i += 256) sWt[i] = Wt[i];
    if (tid < 64) sbt[tid] = bt[tid];
    __syncthreads();
    int wave = tid >> 6, lane = tid & 63;
    int nb = blockIdx.x * 64 + wave * 16;
    if (nb >= n) return;
    int m = lane & 15, q = lane >> 4;
    short* shw = sh + wave * 16 * 72;

    const float* xrow = x + (size_t)(nb + m) * 8;
    float xv[8];
#pragma unroll
    for (int f = 0; f < 8; ++f) xv[f] = xrow[f];

    short8 a0, a1;
#pragma unroll
    for (int j = 0; j < 8; ++j) {
        int c0 = q * 8 + j, c1 = 32 + q * 8 + j;
        float s0 = sbt[c0], s1 = sbt[c1];
#pragma unroll
        for (int f = 0; f < 8; ++f) {
            s0 += xv[f] * sWt[f * 64 + c0];
            s1 += xv[f] * sWt[f * 64 + c1];
        }
        a0[j] = f2bs(fmaxf(s0, 0.f));
        a1[j] = f2bs(fmaxf(s1, 0.f));
    }

    int ty[4];
#pragma unroll
    for (int r = 0; r < 4; ++r) ty[r] = ntype[nb + q * 4 + r];

#pragma unroll
    for (int t = 0; t < 4; ++t) {
        const short* wp = (const short*)(WpT + (size_t)(t * 16 + m) * 64) + q * 8;
        short8 b0 = *(const short8*)(wp);
        short8 b1 = *(const short8*)(wp + 32);
        f32x4 acc = {0.f, 0.f, 0.f, 0.f};
        acc = __builtin_amdgcn_mfma_f32_16x16x32_bf16(a0, b0, acc, 0, 0, 0);
        acc = __builtin_amdgcn_mfma_f32_16x16x32_bf16(a1, b1, acc, 0, 0, 0);
        int col = t * 16 + m;
#pragma unroll
        for (int r = 0; r < 4; ++r) {
            int nd = nb + q * 4 + r;
            short vb = f2bs(acc[r] + TyB[ty[r] * 64 + col]);
            h0b[(size_t)nd * 64 + col] = *reinterpret_cast<bf16*>(&vb);
            shw[(q * 4 + r) * 72 + col] = vb;
        }
    }
    short8 ha0 = *(const short8*)(&shw[m * 72 + q * 8]);
    short8 ha1 = *(const short8*)(&shw[m * 72 + 32 + q * 8]);
#pragma unroll
    for (int t = 0; t < 12; ++t) {
        const short* wp = (const short*)(WT0 + (size_t)(t * 16 + m) * 64) + q * 8;
        short8 b0 = *(const short8*)(wp);
        short8 b1 = *(const short8*)(wp + 32);
        f32x4 acc = {0.f, 0.f, 0.f, 0.f};
        acc = __builtin_amdgcn_mfma_f32_16x16x32_bf16(ha0, b0, acc, 0, 0, 0);
        acc = __builtin_amdgcn_mfma_f32_16x16x32_bf16(ha1, b1, acc, 0, 0, 0);
        int col = t * 16 + m;
        int mat = col >> 6, c = col & 63;
        float bias = (mat == 0) ? bl0[c] : (mat == 1) ? br0[c] : bc0[c];
        bf16* dst = (mat == 0) ? xlo : (mat == 1) ? xro : reso;
#pragma unroll
        for (int r = 0; r < 4; ++r)
            dst[(size_t)(nb + q * 4 + r) * 64 + c] = f2b(acc[r] + bias);
    }
}

// ---------------- CSR scan + degree histogram ----------------
__global__ void k_scan_local(const int* __restrict__ counts, int* __restrict__ row_raw,
                             int* __restrict__ bsum, int* __restrict__ hist, int n) {
    __shared__ int part[256];
    __shared__ int lh[64];
    int tid = threadIdx.x;
    if (tid < 64) lh[tid] = 0;
    __syncthreads();
    int base = blockIdx.x * 1024 + tid * 4;
    int d0 = (base     < n) ? counts[base]     : -1;
    int d1 = (base + 1 < n) ? counts[base + 1] : -1;
    int d2 = (base + 2 < n) ? counts[base + 2] : -1;
    int d3 = (base + 3 < n) ? counts[base + 3] : -1;
    if (d0 >= 0) atomicAdd(&lh[d0 < 63 ? d0 : 63], 1);
    if (d1 >= 0) atomicAdd(&lh[d1 < 63 ? d1 : 63], 1);
    if (d2 >= 0) atomicAdd(&lh[d2 < 63 ? d2 : 63], 1);
    if (d3 >= 0) atomicAdd(&lh[d3 < 63 ? d3 : 63], 1);
    int c0 = d0 + 1, c1 = d1 + 1, c2 = d2 + 1, c3 = d3 + 1;
    part[tid] = c0 + c1 + c2 + c3;
    __syncthreads();
    for (int off = 1; off < 256; off <<= 1) {
        int t = (tid >= off) ? part[tid - off] : 0;
        __syncthreads();
        part[tid] += t;
        __syncthreads();
    }
    int ex = (tid == 0) ? 0 : part[tid - 1];
    if (base     < n) row_raw[base]     = ex;
    if (base + 1 < n) row_raw[base + 1] = ex + c0;
    if (base + 2 < n) row_raw[base + 2] = ex + c0 + c1;
    if (base + 3 < n) row_raw[base + 3] = ex + c0 + c1 + c2;
    if (tid == 255) bsum[blockIdx.x] = part[255];
    if (tid < 64 && lh[tid] > 0) atomicAdd(&hist[tid], lh[tid]);
}

__global__ void k_scan_bsum(int* __restrict__ bsum, int* __restrict__ row_ptr,
                            int* __restrict__ hist, int g, int n) {
    int lane = threadIdx.x;
    int orig = (lane < g) ? bsum[lane] : 0;
    int v = orig;
#pragma unroll
    for (int off = 1; off < 64; off <<= 1) {
        int t = __shfl_up(v, off, 64);
        if (lane >= off) v += t;
    }
    if (lane < g) bsum[lane] = v - orig;
    if (lane == 63) row_ptr[n] = v;

    int ho = hist[lane];
    int hv = ho;
#pragma unroll
    for (int off = 1; off < 64; off <<= 1) {
        int t = __shfl_up(hv, off, 64);
        if (lane >= off) hv += t;
    }
    hist[lane] = hv - ho;
}

__global__ void k_build(const int* __restrict__ src, const int* __restrict__ dst,
                        const int* __restrict__ row_raw, const int* __restrict__ bsum,
                        const int* __restrict__ rank, const int* __restrict__ counts,
                        int* __restrict__ row_ptr, int* __restrict__ csr_src,
                        int* __restrict__ hist, int* __restrict__ perm,
                        int n, int e) {
    __shared__ int lh[64];
    __shared__ int gbase[64];
    int tid = threadIdx.x;
    int i = blockIdx.x * 256 + tid;
    bool nodework = (blockIdx.x * 256) < n;
    if (nodework) {
        if (tid < 64) lh[tid] = 0;
        __syncthreads();
        int bucket = 0, myrank = -1;
        if (i < n) {
            int d = counts[i];
            bucket = d < 63 ? d : 63;
            myrank = atomicAdd(&lh[bucket], 1);
        }
        __syncthreads();
        if (tid < 64 && lh[tid] > 0) gbase[tid] = atomicAdd(&hist[tid], lh[tid]);
        __syncthreads();
        if (i < n) perm[gbase[bucket] + myrank] = i;
    }
    if (i < n) {
        int rp = row_raw[i] + bsum[i >> 10];
        row_ptr[i] = rp;
        csr_src[rp] = i;
    }
    if (i < e) {
        int d = dst[i];
        int pos = row_raw[d] + bsum[d >> 10] + 1 + rank[i];
        csr_src[pos] = src[i];
    }
}

// ---------------- GAT core: per-edge compute step (verified numerics) ----------------
#define GAT_EDGE(XU, LS, A0S, A1S)                                                \
    {                                                                             \
        float x0_ = bflo(XU), x1_ = bfhi(XU);                                     \
        float t0_ = x0_ + xr0; t0_ = fmaxf(t0_, 0.2f * t0_);                      \
        float t1_ = x1_ + xr1; t1_ = fmaxf(t1_, 0.2f * t1_);                      \
        float p_ = t0_ * at0 + t1_ * at1;                                         \
        p_ += __shfl_xor(p_, 1, 64);                                              \
        p_ += __shfl_xor(p_, 2, 64);                                              \
        p_ += __shfl_xor(p_, 4, 64);                                              \
        float pe_ = __expf(fminf(p_, 60.f));                                      \
        A0S += pe_ * x0_;  A1S += pe_ * x1_;  LS += pe_;                          \
    }

// gat phase: ILP-8 phase-separated loads; node ids from perm; result into sh tile
#define GAT_PHASE_BODY                                                            \
    int tid = threadIdx.x;                                                        \
    int wave = tid >> 6, lane = tid & 63;                                         \
    int half = lane >> 5;                                                         \
    int L = lane & 31;                                                            \
    int head = L >> 3, cp = L & 7;                                                \
    int ch = head * 16 + cp * 2;                                                  \
    int nl = wave * 2 + half;                                                     \
    int idx = blockIdx.x * 16 + nl;                                               \
    bool valid = idx < n;                                                         \
    int v = valid ? perm[idx] : 0;                                                \
    if (L == 0) sid[nl] = valid ? v : -1;                                         \
    unsigned int xru = *(const unsigned int*)((const unsigned short*)xr +         \
                                              (size_t)v * 64 + ch);               \
    float xr0 = bflo(xru), xr1 = bfhi(xru);                                       \
    float at0 = att[ch], at1 = att[ch + 1];                                       \
    int beg = row_ptr[v];                                                         \
    int end = valid ? row_ptr[v + 1] : beg;                                       \
    float ls[8] = {0.f, 0.f, 0.f, 0.f, 0.f, 0.f, 0.f, 0.f};                       \
    float a0s[8] = {0.f, 0.f, 0.f, 0.f, 0.f, 0.f, 0.f, 0.f};                      \
    float a1s[8] = {0.f, 0.f, 0.f, 0.f, 0.f, 0.f, 0.f, 0.f};                      \
    int e = beg;                                                                  \
    for (; e + 7 < end; e += 8) {                                                 \
        int sA[8];                                                                \
        _Pragma("unroll")                                                         \
        for (int k = 0; k < 8; ++k) sA[k] = csr_src[e + k];                       \
        unsigned int uA[8];                                                       \
        _Pragma("unroll")                                                         \
        for (int k = 0; k < 8; ++k)                                               \
            uA[k] = *(const unsigned int*)((const unsigned short*)xl +            \
                                           (size_t)sA[k] * 64 + ch);              \
        _Pragma("unroll")                                                         \
        for (int k = 0; k < 8; ++k) GAT_EDGE(uA[k], ls[k], a0s[k], a1s[k])        \
    }                                                                             \
    for (; e < end; ++e) {                                                        \
        int s_ = csr_src[e];                                                      \
        unsigned int u_ = *(const unsigned int*)((const unsigned short*)xl +      \
                                                 (size_t)s_ * 64 + ch);           \
        GAT_EDGE(u_, ls[0], a0s[0], a1s[0])                                       \
    }                                                                             \
    float lsum = ((ls[0] + ls[1]) + (ls[2] + ls[3]))                              \
               + ((ls[4] + ls[5]) + (ls[6] + ls[7]));                             \
    float inv = 1.f / (lsum + 1e-16f);                                            \
    float acc0 = (((a0s[0] + a0s[1]) + (a0s[2] + a0s[3]))                         \
               + ((a0s[4] + a0s[5]) + (a0s[6] + a0s[7]))) * inv;                  \
    float acc1 = (((a1s[0] + a1s[1]) + (a1s[2] + a1s[3]))                         \
               + ((a1s[4] + a1s[5]) + (a1s[6] + a1s[7]))) * inv;                  \
    unsigned int ru = *(const unsigned int*)((const unsigned short*)res +         \
                                             (size_t)v * 64 + ch);                \
    unsigned int hu = *(const unsigned int*)((const unsigned short*)h0b +         \
                                             (size_t)v * 64 + ch);                \
    float o0 = acc0 + bflo(ru);                                                   \
    float o1 = acc1 + bfhi(ru);                                                   \
    float a = alpha_p[0];                                                         \
    float t0 = a * o0 + (1.f - a) * bflo(hu);                                     \
    float t1 = a * o1 + (1.f - a) * bfhi(hu);                                     \
    float mu = t0 + t1;                                                           \
    _Pragma("unroll")                                                             \
    for (int o = 1; o < 32; o <<= 1) mu += __shfl_xor(mu, o, 64);                 \
    mu *= (1.f / 64.f);                                                           \
    float d0 = t0 - mu, d1 = t1 - mu;                                             \
    float var = d0 * d0 + d1 * d1;                                                \
    _Pragma("unroll")                                                             \
    for (int o = 1; o < 32; o <<= 1) var += __shfl_xor(var, o, 64);               \
    var *= (1.f / 64.f);                                                          \
    float rs = rsqrtf(var + 1e-5f);                                               \
    float hn0 = gamma[ch] * d0 * rs + beta[ch];                                   \
    float hn1 = gamma[ch + 1] * d1 * rs + beta[ch + 1];                           \
    *(unsigned int*)((char*)sh + nl * 144 + ch * 2) = packbf(hn0, hn1);           \
    __syncthreads();

// ---------------- gat + next-layer xform fused (16 perm-nodes/block, 512 threads) ----------------
__global__ __launch_bounds__(512) void k_gatx(
        const bf16* __restrict__ xl, const bf16* __restrict__ xr,
        const bf16* __restrict__ res, const bf16* __restrict__ h0b,
        const float* __restrict__ att, const float* __restrict__ gamma,
        const float* __restrict__ beta, const float* __restrict__ alpha_p,
        const int* __restrict__ row_ptr, const int* __restrict__ csr_src,
        const int* __restrict__ perm,
        const bf16* __restrict__ WTn, const float* __restrict__ bln,
        const float* __restrict__ brn, const float* __restrict__ bcn,
        bf16* __restrict__ xlo, bf16* __restrict__ xro, bf16* __restrict__ reso,
        int n) {
    __shared__ __align__(16) short sh[16 * 72];
    __shared__ int sid[16];
    GAT_PHASE_BODY

    int m = lane & 15, q = lane >> 4;
    short8 ha0 = *(const short8*)(&sh[m * 72 + q * 8]);
    short8 ha1 = *(const short8*)(&sh[m * 72 + 32 + q * 8]);
    for (int t = wave; t < 12; t += 8) {
        const short* wp = (const short*)(WTn + (size_t)(t * 16 + m) * 64) + q * 8;
        short8 b0 = *(const short8*)(wp);
        short8 b1 = *(const short8*)(wp + 32);
        f32x4 acc = {0.f, 0.f, 0.f, 0.f};
        acc = __builtin_amdgcn_mfma_f32_16x16x32_bf16(ha0, b0, acc, 0, 0, 0);
        acc = __builtin_amdgcn_mfma_f32_16x16x32_bf16(ha1, b1, acc, 0, 0, 0);
        int col = t * 16 + m;
        int mat = col >> 6, c = col & 63;
        float bias = (mat == 0) ? bln[c] : (mat == 1) ? brn[c] : bcn[c];
        bf16* dst = (mat == 0) ? xlo : (mat == 1) ? xro : reso;
#pragma unroll
        for (int r = 0; r < 4; ++r) {
            int nd = sid[q * 4 + r];
            if (nd >= 0) dst[(size_t)nd * 64 + c] = f2b(acc[r] + bias);
        }
    }
}

// ---------------- last gat + output head fused ----------------
__global__ __launch_bounds__(512) void k_gath(
        const bf16* __restrict__ xl, const bf16* __restrict__ xr,
        const bf16* __restrict__ res, const bf16* __restrict__ h0b,
        const float* __restrict__ att, const float* __restrict__ gamma,
        const float* __restrict__ beta, const float* __restrict__ alpha_p,
        const int* __restrict__ row_ptr, const int* __restrict__ csr_src,
        const int* __restrict__ perm,
        const bf16* __restrict__ W1T, const float* __restrict__ b1,
        const float* __restrict__ W2, const float* __restrict__ b2,
        float* __restrict__ out, int n) {
    __shared__ __align__(16) short sh[16 * 72];
    __shared__ int sid[16];
    GAT_PHASE_BODY

    if (wave == 0) {
        int m = lane & 15, q = lane >> 4;
        short8 ha0 = *(const short8*)(&sh[m * 72 + q * 8]);
        short8 ha1 = *(const short8*)(&sh[m * 72 + 32 + q * 8]);

        const short* w0p = (const short*)(W1T + (size_t)m * 64) + q * 8;
        const short* w1p = (const short*)(W1T + (size_t)(16 + m) * 64) + q * 8;
        short8 b00 = *(const short8*)(w0p);
        short8 b01 = *(const short8*)(w0p + 32);
        short8 b10 = *(const short8*)(w1p);
        short8 b11 = *(const short8*)(w1p + 32);

        f32x4 acc0 = {0.f, 0.f, 0.f, 0.f};
        f32x4 acc1 = {0.f, 0.f, 0.f, 0.f};
        acc0 = __builtin_amdgcn_mfma_f32_16x16x32_bf16(ha0, b00, acc0, 0, 0, 0);
        acc0 = __builtin_amdgcn_mfma_f32_16x16x32_bf16(ha1, b01, acc0, 0, 0, 0);
        acc1 = __builtin_amdgcn_mfma_f32_16x16x32_bf16(ha0, b10, acc1, 0, 0, 0);
        acc1 = __builtin_amdgcn_mfma_f32_16x16x32_bf16(ha1, b11, acc1, 0, 0, 0);

        float w2a = W2[m], w2b = W2[16 + m];
        float bb0 = b1[m], bb1 = b1[16 + m];
        float part[4];
#pragma unroll
        for (int r = 0; r < 4; ++r)
            part[r] = fmaxf(acc0[r] + bb0, 0.f) * w2a + fmaxf(acc1[r] + bb1, 0.f) * w2b;
#pragma unroll
        for (int mask = 1; mask < 16; mask <<= 1) {
#pragma unroll
            for (int r = 0; r < 4; ++r) part[r] += __shfl_xor(part[r], mask, 64);
        }
        if (m == 0) {
            float bb2 = b2[0];
#pragma unroll
            for (int r = 0; r < 4; ++r) {
                int nd = sid[q * 4 + r];
                if (nd >= 0) out[nd] = 1.f / (1.f + __expf(-(part[r] + bb2)));
            }
        }
    }
}

extern "C" void kernel_launch(void* const* d_in, const int* in_sizes, int n_in,
                              void* d_out, int out_size, void* d_ws, size_t ws_size,
                              hipStream_t stream) {
    const float* x     = (const float*)d_in[0];
    const int*   ntype = (const int*)d_in[1];
    const int*   esrc  = (const int*)d_in[2];
    const int*   edst  = (const int*)d_in[3];
    const float* Wt    = (const float*)d_in[4];
    const float* bt    = (const float*)d_in[5];
    const float* Et    = (const float*)d_in[6];
    const float* Wp    = (const float*)d_in[7];
    const float* bp    = (const float*)d_in[8];
    const float* Wl    = (const float*)d_in[9];
    const float* bl    = (const float*)d_in[10];
    const float* Wr    = (const float*)d_in[11];
    const float* br    = (const float*)d_in[12];
    const float* att   = (const float*)d_in[13];
    const float* Wres  = (const float*)d_in[14];
    const float* bconv = (const float*)d_in[15];
    const float* gamma = (const float*)d_in[16];
    const float* beta  = (const float*)d_in[17];
    const float* alpha = (const float*)d_in[18];
    const float* W1    = (const float*)d_in[19];
    const float* b1    = (const float*)d_in[20];
    const float* W2    = (const float*)d_in[21];
    const float* b2    = (const float*)d_in[22];
    float* out = (float*)d_out;

    const int N = in_sizes[1];   // 50000
    const int E = in_sizes[2];   // 800000

    const int G = (N + 1023) / 1024;

    size_t need = 256
                + (size_t)N * 64 * 2 * 7
                + (size_t)36864 * 2 + (size_t)4096 * 2 + (size_t)2048 * 2
                + (size_t)192 * 4
                + (size_t)N * 4
                + (size_t)(N + 1) * 4
                + (size_t)(N + 64) * 4
                + (size_t)N * 4
                + (size_t)E * 4
                + 256
                + (size_t)(E + N) * 4;

    if (ws_size < need) {
        k_sentinel<<<(N + 255) / 256, 256, 0, stream>>>(out, N,
                                                        100.0f + (float)(ws_size >> 20));
        return;
    }

    char* ws = (char*)d_ws;
    ws += 256;
    bf16* h0b   = (bf16*)ws;  ws += (size_t)N * 64 * 2;
    bf16* xlA   = (bf16*)ws;  ws += (size_t)N * 64 * 2;
    bf16* xrA   = (bf16*)ws;  ws += (size_t)N * 64 * 2;
    bf16* resA  = (bf16*)ws;  ws += (size_t)N * 64 * 2;
    bf16* xlB   = (bf16*)ws;  ws += (size_t)N * 64 * 2;
    bf16* xrB   = (bf16*)ws;  ws += (size_t)N * 64 * 2;
    bf16* resB  = (bf16*)ws;  ws += (size_t)N * 64 * 2;
    bf16* WT    = (bf16*)ws;  ws += (size_t)36864 * 2;
    bf16* WpT   = (bf16*)ws;  ws += (size_t)4096 * 2;
    bf16* W1T   = (bf16*)ws;  ws += (size_t)2048 * 2;
    float* TyB  = (float*)ws; ws += (size_t)192 * 4;
    int* row_raw = (int*)ws;  ws += (size_t)N * 4;
    int* row_ptr = (int*)ws;  ws += (size_t)(N + 1) * 4;
    int* counts  = (int*)ws;  ws += (size_t)N * 4;
    int* hist    = (int*)ws;  ws += (size_t)64 * 4;
    int* perm    = (int*)ws;  ws += (size_t)N * 4;
    int* rank    = (int*)ws;  ws += (size_t)E * 4;
    int* bsum    = (int*)ws;  ws += 256;
    int* csr_src = (int*)ws;  ws += (size_t)(E + N) * 4;

    hipMemsetAsync(counts, 0, (size_t)(N + 64) * 4, stream);
    k_setup<<<PREP_BLOCKS + (E + 255) / 256, 256, 0, stream>>>(
        Wl, Wr, Wres, Wp, W1, Et, bp, WT, WpT, W1T, TyB, edst, counts, rank, E);
    k_encx<<<(N + 63) / 64, 256, 0, stream>>>(x, ntype, Wt, bt, WpT, TyB, h0b,
                                              WT, bl, br, bconv, xlA, xrA, resA, N);
    k_scan_local<<<G, 256, 0, stream>>>(counts, row_raw, bsum, hist, N);
    k_scan_bsum<<<1, 64, 0, stream>>>(bsum, row_ptr, hist, G, N);
    k_build<<<(E + 255) / 256, 256, 0, stream>>>(esrc, edst, row_raw, bsum, rank,
                                                 counts, row_ptr, csr_src, hist, perm,
                                                 N, E);

    k_gatx<<<(N + 15) / 16, 512, 0, stream>>>(
        xlA, xrA, resA, h0b, att, gamma, beta, alpha, row_ptr, csr_src, perm,
        WT + 12288, bl + 64, br + 64, bconv + 64, xlB, xrB, resB, N);
    k_gatx<<<(N + 15) / 16, 512, 0, stream>>>(
        xlB, xrB, resB, h0b, att + 64, gamma + 64, beta + 64, alpha, row_ptr, csr_src,
        perm, WT + 24576, bl + 128, br + 128, bconv + 128, xlA, xrA, resA, N);
    k_gath<<<(N + 15) / 16, 512, 0, stream>>>(
        xlA, xrA, resA, h0b, att + 128, gamma + 128, beta + 128, alpha,
        row_ptr, csr_src, perm, W1T, b1, W2, b2, out, N);
}

// Round 19
// 314.969 us; speedup vs baseline: 1.1551x; 1.1551x over previous
//
#include <hip/hip_runtime.h>
#include <hip/hip_bf16.h>

typedef __hip_bfloat16 bf16;
typedef __attribute__((ext_vector_type(8))) short short8;
typedef __attribute__((ext_vector_type(4))) float f32x4;

__device__ __forceinline__ float b2f(bf16 v) { return __bfloat162float(v); }
__device__ __forceinline__ bf16 f2b(float v) { return __float2bfloat16(v); }
__device__ __forceinline__ short f2bs(float v) {
    bf16 b = f2b(v);
    return *reinterpret_cast<short*>(&b);
}
__device__ __forceinline__ float bflo(unsigned int u) { return __uint_as_float(u << 16); }
__device__ __forceinline__ float bfhi(unsigned int u) { return __uint_as_float(u & 0xffff0000u); }
__device__ __forceinline__ unsigned int packbf(float lo, float hi) {
    bf16 l = f2b(lo), h = f2b(hi);
    return ((unsigned int)(*(unsigned short*)&h) << 16) | (*(unsigned short*)&l);
}

// DTYPE (resolved rounds 0-9): inputs fp32, output fp32; intermediates bf16.
// ILP note (r18): ILP-8 in the gat loop costs 16 VGPR -> occupancy 57->35% and
// REGRESSES (+17 us/dispatch). ILP-4 (this version) is the measured sweet spot.

__global__ void k_sentinel(float* out, int n, float val) {
    int i = blockIdx.x * blockDim.x + threadIdx.x;
    if (i < n) out[i] = val;
}

// ---------------- setup: weight repacks + TyB (blocks 0..168) || edge count (rest) ----------------
#define PREP_BLOCKS 169
__global__ void k_setup(const float* __restrict__ Wl, const float* __restrict__ Wr,
                        const float* __restrict__ Wres, const float* __restrict__ Wp,
                        const float* __restrict__ W1, const float* __restrict__ Et,
                        const float* __restrict__ bp,
                        bf16* __restrict__ WT, bf16* __restrict__ WpT,
                        bf16* __restrict__ W1T, float* __restrict__ TyB,
                        const int* __restrict__ edst, int* __restrict__ counts,
                        int* __restrict__ rank, int e) {
    int b = blockIdx.x;
    if (b < PREP_BLOCKS) {
        int i = b * 256 + threadIdx.x;
        if (i < 36864) {
            int l = i / 12288, rem = i % 12288;
            int col = rem / 64, k = rem % 64;
            int mat = col >> 6, c = col & 63;
            const float* W = (mat == 0) ? Wl : (mat == 1) ? Wr : Wres;
            WT[i] = f2b(W[l * 4096 + k * 64 + c]);
        } else if (i < 40960) {
            int j = i - 36864, col = j / 64, k = j % 64;
            WpT[j] = f2b(Wp[k * 64 + col]);
        } else if (i < 43008) {
            int j = i - 40960, col = j / 64, k = j % 64;
            W1T[j] = f2b(W1[k * 32 + col]);
        } else if (i < 43200) {
            int j = i - 43008, t = j / 64, d = j % 64;
            float s = bp[d];
#pragma unroll
            for (int f = 0; f < 16; ++f) s += Et[t * 16 + f] * Wp[(64 + f) * 64 + d];
            TyB[j] = s;
        }
    } else {
        int i = (b - PREP_BLOCKS) * 256 + threadIdx.x;
        if (i < e) rank[i] = atomicAdd(&counts[edst[i]], 1);
    }
}

// ---------------- encoder + layer-0 xform fused ----------------
__global__ __launch_bounds__(256) void k_encx(
        const float* __restrict__ x, const int* __restrict__ ntype,
        const float* __restrict__ Wt, const float* __restrict__ bt,
        const bf16* __restrict__ WpT, const float* __restrict__ TyB,
        bf16* __restrict__ h0b,
        const bf16* __restrict__ WT0, const float* __restrict__ bl0,
        const float* __restrict__ br0, const float* __restrict__ bc0,
        bf16* __restrict__ xlo, bf16* __restrict__ xro, bf16* __restrict__ reso,
        int n) {
    __shared__ float sWt[512];
    __shared__ float sbt[64];
    __shared__ __align__(16) short sh[4 * 16 * 72];
    int tid = threadIdx.x;
    for (int i = tid; i < 512; i += 256) sWt[i] = Wt[i];
    if (tid < 64) sbt[tid] = bt[tid];
    __syncthreads();
    int wave = tid >> 6, lane = tid & 63;
    int nb = blockIdx.x * 64 + wave * 16;
    if (nb >= n) return;
    int m = lane & 15, q = lane >> 4;
    short* shw = sh + wave * 16 * 72;

    const float* xrow = x + (size_t)(nb + m) * 8;
    float xv[8];
#pragma unroll
    for (int f = 0; f < 8; ++f) xv[f] = xrow[f];

    short8 a0, a1;
#pragma unroll
    for (int j = 0; j < 8; ++j) {
        int c0 = q * 8 + j, c1 = 32 + q * 8 + j;
        float s0 = sbt[c0], s1 = sbt[c1];
#pragma unroll
        for (int f = 0; f < 8; ++f) {
            s0 += xv[f] * sWt[f * 64 + c0];
            s1 += xv[f] * sWt[f * 64 + c1];
        }
        a0[j] = f2bs(fmaxf(s0, 0.f));
        a1[j] = f2bs(fmaxf(s1, 0.f));
    }

    int ty[4];
#pragma unroll
    for (int r = 0; r < 4; ++r) ty[r] = ntype[nb + q * 4 + r];

#pragma unroll
    for (int t = 0; t < 4; ++t) {
        const short* wp = (const short*)(WpT + (size_t)(t * 16 + m) * 64) + q * 8;
        short8 b0 = *(const short8*)(wp);
        short8 b1 = *(const short8*)(wp + 32);
        f32x4 acc = {0.f, 0.f, 0.f, 0.f};
        acc = __builtin_amdgcn_mfma_f32_16x16x32_bf16(a0, b0, acc, 0, 0, 0);
        acc = __builtin_amdgcn_mfma_f32_16x16x32_bf16(a1, b1, acc, 0, 0, 0);
        int col = t * 16 + m;
#pragma unroll
        for (int r = 0; r < 4; ++r) {
            int nd = nb + q * 4 + r;
            short vb = f2bs(acc[r] + TyB[ty[r] * 64 + col]);
            h0b[(size_t)nd * 64 + col] = *reinterpret_cast<bf16*>(&vb);
            shw[(q * 4 + r) * 72 + col] = vb;
        }
    }
    short8 ha0 = *(const short8*)(&shw[m * 72 + q * 8]);
    short8 ha1 = *(const short8*)(&shw[m * 72 + 32 + q * 8]);
#pragma unroll
    for (int t = 0; t < 12; ++t) {
        const short* wp = (const short*)(WT0 + (size_t)(t * 16 + m) * 64) + q * 8;
        short8 b0 = *(const short8*)(wp);
        short8 b1 = *(const short8*)(wp + 32);
        f32x4 acc = {0.f, 0.f, 0.f, 0.f};
        acc = __builtin_amdgcn_mfma_f32_16x16x32_bf16(ha0, b0, acc, 0, 0, 0);
        acc = __builtin_amdgcn_mfma_f32_16x16x32_bf16(ha1, b1, acc, 0, 0, 0);
        int col = t * 16 + m;
        int mat = col >> 6, c = col & 63;
        float bias = (mat == 0) ? bl0[c] : (mat == 1) ? br0[c] : bc0[c];
        bf16* dst = (mat == 0) ? xlo : (mat == 1) ? xro : reso;
#pragma unroll
        for (int r = 0; r < 4; ++r)
            dst[(size_t)(nb + q * 4 + r) * 64 + c] = f2b(acc[r] + bias);
    }
}

// ---------------- CSR scan + degree histogram ----------------
__global__ void k_scan_local(const int* __restrict__ counts, int* __restrict__ row_raw,
                             int* __restrict__ bsum, int* __restrict__ hist, int n) {
    __shared__ int part[256];
    __shared__ int lh[64];
    int tid = threadIdx.x;
    if (tid < 64) lh[tid] = 0;
    __syncthreads();
    int base = blockIdx.x * 1024 + tid * 4;
    int d0 = (base     < n) ? counts[base]     : -1;
    int d1 = (base + 1 < n) ? counts[base + 1] : -1;
    int d2 = (base + 2 < n) ? counts[base + 2] : -1;
    int d3 = (base + 3 < n) ? counts[base + 3] : -1;
    if (d0 >= 0) atomicAdd(&lh[d0 < 63 ? d0 : 63], 1);
    if (d1 >= 0) atomicAdd(&lh[d1 < 63 ? d1 : 63], 1);
    if (d2 >= 0) atomicAdd(&lh[d2 < 63 ? d2 : 63], 1);
    if (d3 >= 0) atomicAdd(&lh[d3 < 63 ? d3 : 63], 1);
    int c0 = d0 + 1, c1 = d1 + 1, c2 = d2 + 1, c3 = d3 + 1;
    part[tid] = c0 + c1 + c2 + c3;
    __syncthreads();
    for (int off = 1; off < 256; off <<= 1) {
        int t = (tid >= off) ? part[tid - off] : 0;
        __syncthreads();
        part[tid] += t;
        __syncthreads();
    }
    int ex = (tid == 0) ? 0 : part[tid - 1];
    if (base     < n) row_raw[base]     = ex;
    if (base + 1 < n) row_raw[base + 1] = ex + c0;
    if (base + 2 < n) row_raw[base + 2] = ex + c0 + c1;
    if (base + 3 < n) row_raw[base + 3] = ex + c0 + c1 + c2;
    if (tid == 255) bsum[blockIdx.x] = part[255];
    if (tid < 64 && lh[tid] > 0) atomicAdd(&hist[tid], lh[tid]);
}

__global__ void k_scan_bsum(int* __restrict__ bsum, int* __restrict__ row_ptr,
                            int* __restrict__ hist, int g, int n) {
    int lane = threadIdx.x;
    int orig = (lane < g) ? bsum[lane] : 0;
    int v = orig;
#pragma unroll
    for (int off = 1; off < 64; off <<= 1) {
        int t = __shfl_up(v, off, 64);
        if (lane >= off) v += t;
    }
    if (lane < g) bsum[lane] = v - orig;
    if (lane == 63) row_ptr[n] = v;

    int ho = hist[lane];
    int hv = ho;
#pragma unroll
    for (int off = 1; off < 64; off <<= 1) {
        int t = __shfl_up(hv, off, 64);
        if (lane >= off) hv += t;
    }
    hist[lane] = hv - ho;
}

__global__ void k_build(const int* __restrict__ src, const int* __restrict__ dst,
                        const int* __restrict__ row_raw, const int* __restrict__ bsum,
                        const int* __restrict__ rank, const int* __restrict__ counts,
                        int* __restrict__ row_ptr, int* __restrict__ csr_src,
                        int* __restrict__ hist, int* __restrict__ perm,
                        int n, int e) {
    __shared__ int lh[64];
    __shared__ int gbase[64];
    int tid = threadIdx.x;
    int i = blockIdx.x * 256 + tid;
    bool nodework = (blockIdx.x * 256) < n;
    if (nodework) {
        if (tid < 64) lh[tid] = 0;
        __syncthreads();
        int bucket = 0, myrank = -1;
        if (i < n) {
            int d = counts[i];
            bucket = d < 63 ? d : 63;
            myrank = atomicAdd(&lh[bucket], 1);
        }
        __syncthreads();
        if (tid < 64 && lh[tid] > 0) gbase[tid] = atomicAdd(&hist[tid], lh[tid]);
        __syncthreads();
        if (i < n) perm[gbase[bucket] + myrank] = i;
    }
    if (i < n) {
        int rp = row_raw[i] + bsum[i >> 10];
        row_ptr[i] = rp;
        csr_src[rp] = i;
    }
    if (i < e) {
        int d = dst[i];
        int pos = row_raw[d] + bsum[d >> 10] + 1 + rank[i];
        csr_src[pos] = src[i];
    }
}

// ---------------- GAT core (verified round-15 numerics) ----------------
#define GAT2_STEP(E_IDX, LS, A0S, A1S)                                            \
    {                                                                             \
        int s_ = csr_src[E_IDX];                                                  \
        unsigned int xu_ = *(const unsigned int*)((const unsigned short*)xl +     \
                                                  (size_t)s_ * 64 + ch);          \
        float x0_ = bflo(xu_), x1_ = bfhi(xu_);                                   \
        float t0_ = x0_ + xr0; t0_ = fmaxf(t0_, 0.2f * t0_);                      \
        float t1_ = x1_ + xr1; t1_ = fmaxf(t1_, 0.2f * t1_);                      \
        float p_ = t0_ * at0 + t1_ * at1;                                         \
        p_ += __shfl_xor(p_, 1, 64);                                              \
        p_ += __shfl_xor(p_, 2, 64);                                              \
        p_ += __shfl_xor(p_, 4, 64);                                              \
        float pe_ = __expf(fminf(p_, 60.f));                                      \
        A0S += pe_ * x0_;  A1S += pe_ * x1_;  LS += pe_;                          \
    }

// gat phase: node ids from perm; result into sh tile; ids into sid
#define GAT_PHASE_BODY                                                            \
    int tid = threadIdx.x;                                                        \
    int wave = tid >> 6, lane = tid & 63;                                         \
    int half = lane >> 5;                                                         \
    int L = lane & 31;                                                            \
    int head = L >> 3, cp = L & 7;                                                \
    int ch = head * 16 + cp * 2;                                                  \
    int nl = wave * 2 + half;                                                     \
    int idx = blockIdx.x * 16 + nl;                                               \
    bool valid = idx < n;                                                         \
    int v = valid ? perm[idx] : 0;                                                \
    if (L == 0) sid[nl] = valid ? v : -1;                                         \
    unsigned int xru = *(const unsigned int*)((const unsigned short*)xr +         \
                                              (size_t)v * 64 + ch);               \
    float xr0 = bflo(xru), xr1 = bfhi(xru);                                       \
    float at0 = att[ch], at1 = att[ch + 1];                                       \
    int beg = row_ptr[v];                                                         \
    int end = valid ? row_ptr[v + 1] : beg;                                       \
    float l0 = 0.f, A00 = 0.f, A01 = 0.f;                                         \
    float l1 = 0.f, A10 = 0.f, A11 = 0.f;                                         \
    float l2 = 0.f, A20 = 0.f, A21 = 0.f;                                         \
    float l3 = 0.f, A30 = 0.f, A31 = 0.f;                                         \
    int e = beg;                                                                  \
    for (; e + 3 < end; e += 4) {                                                 \
        GAT2_STEP(e,     l0, A00, A01)                                            \
        GAT2_STEP(e + 1, l1, A10, A11)                                            \
        GAT2_STEP(e + 2, l2, A20, A21)                                            \
        GAT2_STEP(e + 3, l3, A30, A31)                                            \
    }                                                                             \
    int rem = end - e;                                                            \
    if (rem > 0) GAT2_STEP(e,     l0, A00, A01)                                   \
    if (rem > 1) GAT2_STEP(e + 1, l1, A10, A11)                                   \
    if (rem > 2) GAT2_STEP(e + 2, l2, A20, A21)                                   \
    float lsum = (l0 + l1) + (l2 + l3);                                           \
    float inv = 1.f / (lsum + 1e-16f);                                            \
    float acc0 = ((A00 + A10) + (A20 + A30)) * inv;                               \
    float acc1 = ((A01 + A11) + (A21 + A31)) * inv;                               \
    unsigned int ru = *(const unsigned int*)((const unsigned short*)res +         \
                                             (size_t)v * 64 + ch);                \
    unsigned int hu = *(const unsigned int*)((const unsigned short*)h0b +         \
                                             (size_t)v * 64 + ch);                \
    float o0 = acc0 + bflo(ru);                                                   \
    float o1 = acc1 + bfhi(ru);                                                   \
    float a = alpha_p[0];                                                         \
    float t0 = a * o0 + (1.f - a) * bflo(hu);                                     \
    float t1 = a * o1 + (1.f - a) * bfhi(hu);                                     \
    float mu = t0 + t1;                                                           \
    _Pragma("unroll")                                                             \
    for (int o = 1; o < 32; o <<= 1) mu += __shfl_xor(mu, o, 64);                 \
    mu *= (1.f / 64.f);                                                           \
    float d0 = t0 - mu, d1 = t1 - mu;                                             \
    float var = d0 * d0 + d1 * d1;                                                \
    _Pragma("unroll")                                                             \
    for (int o = 1; o < 32; o <<= 1) var += __shfl_xor(var, o, 64);               \
    var *= (1.f / 64.f);                                                          \
    float rs = rsqrtf(var + 1e-5f);                                               \
    float hn0 = gamma[ch] * d0 * rs + beta[ch];                                   \
    float hn1 = gamma[ch + 1] * d1 * rs + beta[ch + 1];                           \
    *(unsigned int*)((char*)sh + nl * 144 + ch * 2) = packbf(hn0, hn1);           \
    __syncthreads();

// ---------------- gat + next-layer xform fused (16 perm-nodes/block, 512 threads) ----------------
__global__ __launch_bounds__(512) void k_gatx(
        const bf16* __restrict__ xl, const bf16* __restrict__ xr,
        const bf16* __restrict__ res, const bf16* __restrict__ h0b,
        const float* __restrict__ att, const float* __restrict__ gamma,
        const float* __restrict__ beta, const float* __restrict__ alpha_p,
        const int* __restrict__ row_ptr, const int* __restrict__ csr_src,
        const int* __restrict__ perm,
        const bf16* __restrict__ WTn, const float* __restrict__ bln,
        const float* __restrict__ brn, const float* __restrict__ bcn,
        bf16* __restrict__ xlo, bf16* __restrict__ xro, bf16* __restrict__ reso,
        int n) {
    __shared__ __align__(16) short sh[16 * 72];
    __shared__ int sid[16];
    GAT_PHASE_BODY

    int m = lane & 15, q = lane >> 4;
    short8 ha0 = *(const short8*)(&sh[m * 72 + q * 8]);
    short8 ha1 = *(const short8*)(&sh[m * 72 + 32 + q * 8]);
    for (int t = wave; t < 12; t += 8) {
        const short* wp = (const short*)(WTn + (size_t)(t * 16 + m) * 64) + q * 8;
        short8 b0 = *(const short8*)(wp);
        short8 b1 = *(const short8*)(wp + 32);
        f32x4 acc = {0.f, 0.f, 0.f, 0.f};
        acc = __builtin_amdgcn_mfma_f32_16x16x32_bf16(ha0, b0, acc, 0, 0, 0);
        acc = __builtin_amdgcn_mfma_f32_16x16x32_bf16(ha1, b1, acc, 0, 0, 0);
        int col = t * 16 + m;
        int mat = col >> 6, c = col & 63;
        float bias = (mat == 0) ? bln[c] : (mat == 1) ? brn[c] : bcn[c];
        bf16* dst = (mat == 0) ? xlo : (mat == 1) ? xro : reso;
#pragma unroll
        for (int r = 0; r < 4; ++r) {
            int nd = sid[q * 4 + r];
            if (nd >= 0) dst[(size_t)nd * 64 + c] = f2b(acc[r] + bias);
        }
    }
}

// ---------------- last gat + output head fused ----------------
__global__ __launch_bounds__(512) void k_gath(
        const bf16* __restrict__ xl, const bf16* __restrict__ xr,
        const bf16* __restrict__ res, const bf16* __restrict__ h0b,
        const float* __restrict__ att, const float* __restrict__ gamma,
        const float* __restrict__ beta, const float* __restrict__ alpha_p,
        const int* __restrict__ row_ptr, const int* __restrict__ csr_src,
        const int* __restrict__ perm,
        const bf16* __restrict__ W1T, const float* __restrict__ b1,
        const float* __restrict__ W2, const float* __restrict__ b2,
        float* __restrict__ out, int n) {
    __shared__ __align__(16) short sh[16 * 72];
    __shared__ int sid[16];
    GAT_PHASE_BODY

    if (wave == 0) {
        int m = lane & 15, q = lane >> 4;
        short8 ha0 = *(const short8*)(&sh[m * 72 + q * 8]);
        short8 ha1 = *(const short8*)(&sh[m * 72 + 32 + q * 8]);

        const short* w0p = (const short*)(W1T + (size_t)m * 64) + q * 8;
        const short* w1p = (const short*)(W1T + (size_t)(16 + m) * 64) + q * 8;
        short8 b00 = *(const short8*)(w0p);
        short8 b01 = *(const short8*)(w0p + 32);
        short8 b10 = *(const short8*)(w1p);
        short8 b11 = *(const short8*)(w1p + 32);

        f32x4 acc0 = {0.f, 0.f, 0.f, 0.f};
        f32x4 acc1 = {0.f, 0.f, 0.f, 0.f};
        acc0 = __builtin_amdgcn_mfma_f32_16x16x32_bf16(ha0, b00, acc0, 0, 0, 0);
        acc0 = __builtin_amdgcn_mfma_f32_16x16x32_bf16(ha1, b01, acc0, 0, 0, 0);
        acc1 = __builtin_amdgcn_mfma_f32_16x16x32_bf16(ha0, b10, acc1, 0, 0, 0);
        acc1 = __builtin_amdgcn_mfma_f32_16x16x32_bf16(ha1, b11, acc1, 0, 0, 0);

        float w2a = W2[m], w2b = W2[16 + m];
        float bb0 = b1[m], bb1 = b1[16 + m];
        float part[4];
#pragma unroll
        for (int r = 0; r < 4; ++r)
            part[r] = fmaxf(acc0[r] + bb0, 0.f) * w2a + fmaxf(acc1[r] + bb1, 0.f) * w2b;
#pragma unroll
        for (int mask = 1; mask < 16; mask <<= 1) {
#pragma unroll
            for (int r = 0; r < 4; ++r) part[r] += __shfl_xor(part[r], mask, 64);
        }
        if (m == 0) {
            float bb2 = b2[0];
#pragma unroll
            for (int r = 0; r < 4; ++r) {
                int nd = sid[q * 4 + r];
                if (nd >= 0) out[nd] = 1.f / (1.f + __expf(-(part[r] + bb2)));
            }
        }
    }
}

extern "C" void kernel_launch(void* const* d_in, const int* in_sizes, int n_in,
                              void* d_out, int out_size, void* d_ws, size_t ws_size,
                              hipStream_t stream) {
    const float* x     = (const float*)d_in[0];
    const int*   ntype = (const int*)d_in[1];
    const int*   esrc  = (const int*)d_in[2];
    const int*   edst  = (const int*)d_in[3];
    const float* Wt    = (const float*)d_in[4];
    const float* bt    = (const float*)d_in[5];
    const float* Et    = (const float*)d_in[6];
    const float* Wp    = (const float*)d_in[7];
    const float* bp    = (const float*)d_in[8];
    const float* Wl    = (const float*)d_in[9];
    const float* bl    = (const float*)d_in[10];
    const float* Wr    = (const float*)d_in[11];
    const float* br    = (const float*)d_in[12];
    const float* att   = (const float*)d_in[13];
    const float* Wres  = (const float*)d_in[14];
    const float* bconv = (const float*)d_in[15];
    const float* gamma = (const float*)d_in[16];
    const float* beta  = (const float*)d_in[17];
    const float* alpha = (const float*)d_in[18];
    const float* W1    = (const float*)d_in[19];
    const float* b1    = (const float*)d_in[20];
    const float* W2    = (const float*)d_in[21];
    const float* b2    = (const float*)d_in[22];
    float* out = (float*)d_out;

    const int N = in_sizes[1];   // 50000
    const int E = in_sizes[2];   // 800000

    const int G = (N + 1023) / 1024;

    size_t need = 256
                + (size_t)N * 64 * 2 * 7
                + (size_t)36864 * 2 + (size_t)4096 * 2 + (size_t)2048 * 2
                + (size_t)192 * 4
                + (size_t)N * 4
                + (size_t)(N + 1) * 4
                + (size_t)(N + 64) * 4
                + (size_t)N * 4
                + (size_t)E * 4
                + 256
                + (size_t)(E + N) * 4;

    if (ws_size < need) {
        k_sentinel<<<(N + 255) / 256, 256, 0, stream>>>(out, N,
                                                        100.0f + (float)(ws_size >> 20));
        return;
    }

    char* ws = (char*)d_ws;
    ws += 256;
    bf16* h0b   = (bf16*)ws;  ws += (size_t)N * 64 * 2;
    bf16* xlA   = (bf16*)ws;  ws += (size_t)N * 64 * 2;
    bf16* xrA   = (bf16*)ws;  ws += (size_t)N * 64 * 2;
    bf16* resA  = (bf16*)ws;  ws += (size_t)N * 64 * 2;
    bf16* xlB   = (bf16*)ws;  ws += (size_t)N * 64 * 2;
    bf16* xrB   = (bf16*)ws;  ws += (size_t)N * 64 * 2;
    bf16* resB  = (bf16*)ws;  ws += (size_t)N * 64 * 2;
    bf16* WT    = (bf16*)ws;  ws += (size_t)36864 * 2;
    bf16* WpT   = (bf16*)ws;  ws += (size_t)4096 * 2;
    bf16* W1T   = (bf16*)ws;  ws += (size_t)2048 * 2;
    float* TyB  = (float*)ws; ws += (size_t)192 * 4;
    int* row_raw = (int*)ws;  ws += (size_t)N * 4;
    int* row_ptr = (int*)ws;  ws += (size_t)(N + 1) * 4;
    int* counts  = (int*)ws;  ws += (size_t)N * 4;
    int* hist    = (int*)ws;  ws += (size_t)64 * 4;
    int* perm    = (int*)ws;  ws += (size_t)N * 4;
    int* rank    = (int*)ws;  ws += (size_t)E * 4;
    int* bsum    = (int*)ws;  ws += 256;
    int* csr_src = (int*)ws;  ws += (size_t)(E + N) * 4;

    hipMemsetAsync(counts, 0, (size_t)(N + 64) * 4, stream);
    k_setup<<<PREP_BLOCKS + (E + 255) / 256, 256, 0, stream>>>(
        Wl, Wr, Wres, Wp, W1, Et, bp, WT, WpT, W1T, TyB, edst, counts, rank, E);
    k_encx<<<(N + 63) / 64, 256, 0, stream>>>(x, ntype, Wt, bt, WpT, TyB, h0b,
                                              WT, bl, br, bconv, xlA, xrA, resA, N);
    k_scan_local<<<G, 256, 0, stream>>>(counts, row_raw, bsum, hist, N);
    k_scan_bsum<<<1, 64, 0, stream>>>(bsum, row_ptr, hist, G, N);
    k_build<<<(E + 255) / 256, 256, 0, stream>>>(esrc, edst, row_raw, bsum, rank,
                                                 counts, row_ptr, csr_src, hist, perm,
                                                 N, E);

    k_gatx<<<(N + 15) / 16, 512, 0, stream>>>(
        xlA, xrA, resA, h0b, att, gamma, beta, alpha, row_ptr, csr_src, perm,
        WT + 12288, bl + 64, br + 64, bconv + 64, xlB, xrB, resB, N);
    k_gatx<<<(N + 15) / 16, 512, 0, stream>>>(
        xlB, xrB, resB, h0b, att + 64, gamma + 64, beta + 64, alpha, row_ptr, csr_src,
        perm, WT + 24576, bl + 128, br + 128, bconv + 128, xlA, xrA, resA, N);
    k_gath<<<(N + 15) / 16, 512, 0, stream>>>(
        xlA, xrA, resA, h0b, att + 128, gamma + 128, beta + 128, alpha,
        row_ptr, csr_src, perm, W1T, b1, W2, b2, out, N);
}

// Round 20
// 299.843 us; speedup vs baseline: 1.2134x; 1.0504x over previous
//
#include <hip/hip_runtime.h>
#include <hip/hip_bf16.h>

typedef __hip_bfloat16 bf16;
typedef __attribute__((ext_vector_type(8))) short short8;
typedef __attribute__((ext_vector_type(4))) float f32x4;

__device__ __forceinline__ float b2f(bf16 v) { return __bfloat162float(v); }
__device__ __forceinline__ bf16 f2b(float v) { return __float2bfloat16(v); }
__device__ __forceinline__ short f2bs(float v) {
    bf16 b = f2b(v);
    return *reinterpret_cast<short*>(&b);
}
__device__ __forceinline__ float bflo(unsigned int u) { return __uint_as_float(u << 16); }
__device__ __forceinline__ float bfhi(unsigned int u) { return __uint_as_float(u & 0xffff0000u); }
__device__ __forceinline__ unsigned int packbf(float lo, float hi) {
    bf16 l = f2b(lo), h = f2b(hi);
    return ((unsigned int)(*(unsigned short*)&h) << 16) | (*(unsigned short*)&l);
}

// DTYPE (resolved rounds 0-9): inputs fp32, output fp32; intermediates bf16.
// ILP note (r18): ILP-8 in the gat loop costs 16 VGPR -> occupancy 57->35% and
// REGRESSES. ILP-4 is the measured sweet spot.
// Perm note (r20): buckets emitted DESCENDING by degree (LPT dispatch order) so
// heavy blocks launch first and short blocks backfill the tail.

__global__ void k_sentinel(float* out, int n, float val) {
    int i = blockIdx.x * blockDim.x + threadIdx.x;
    if (i < n) out[i] = val;
}

// ---------------- setup: weight repacks + TyB (blocks 0..168) || edge count (rest) ----------------
#define PREP_BLOCKS 169
__global__ void k_setup(const float* __restrict__ Wl, const float* __restrict__ Wr,
                        const float* __restrict__ Wres, const float* __restrict__ Wp,
                        const float* __restrict__ W1, const float* __restrict__ Et,
                        const float* __restrict__ bp,
                        bf16* __restrict__ WT, bf16* __restrict__ WpT,
                        bf16* __restrict__ W1T, float* __restrict__ TyB,
                        const int* __restrict__ edst, int* __restrict__ counts,
                        int* __restrict__ rank, int e) {
    int b = blockIdx.x;
    if (b < PREP_BLOCKS) {
        int i = b * 256 + threadIdx.x;
        if (i < 36864) {
            int l = i / 12288, rem = i % 12288;
            int col = rem / 64, k = rem % 64;
            int mat = col >> 6, c = col & 63;
            const float* W = (mat == 0) ? Wl : (mat == 1) ? Wr : Wres;
            WT[i] = f2b(W[l * 4096 + k * 64 + c]);
        } else if (i < 40960) {
            int j = i - 36864, col = j / 64, k = j % 64;
            WpT[j] = f2b(Wp[k * 64 + col]);
        } else if (i < 43008) {
            int j = i - 40960, col = j / 64, k = j % 64;
            W1T[j] = f2b(W1[k * 32 + col]);
        } else if (i < 43200) {
            int j = i - 43008, t = j / 64, d = j % 64;
            float s = bp[d];
#pragma unroll
            for (int f = 0; f < 16; ++f) s += Et[t * 16 + f] * Wp[(64 + f) * 64 + d];
            TyB[j] = s;
        }
    } else {
        int i = (b - PREP_BLOCKS) * 256 + threadIdx.x;
        if (i < e) rank[i] = atomicAdd(&counts[edst[i]], 1);
    }
}

// ---------------- encoder + layer-0 xform fused ----------------
__global__ __launch_bounds__(256) void k_encx(
        const float* __restrict__ x, const int* __restrict__ ntype,
        const float* __restrict__ Wt, const float* __restrict__ bt,
        const bf16* __restrict__ WpT, const float* __restrict__ TyB,
        bf16* __restrict__ h0b,
        const bf16* __restrict__ WT0, const float* __restrict__ bl0,
        const float* __restrict__ br0, const float* __restrict__ bc0,
        bf16* __restrict__ xlo, bf16* __restrict__ xro, bf16* __restrict__ reso,
        int n) {
    __shared__ float sWt[512];
    __shared__ float sbt[64];
    __shared__ __align__(16) short sh[4 * 16 * 72];
    int tid = threadIdx.x;
    for (int i = tid; i < 512; i += 256) sWt[i] = Wt[i];
    if (tid < 64) sbt[tid] = bt[tid];
    __syncthreads();
    int wave = tid >> 6, lane = tid & 63;
    int nb = blockIdx.x * 64 + wave * 16;
    if (nb >= n) return;
    int m = lane & 15, q = lane >> 4;
    short* shw = sh + wave * 16 * 72;

    const float* xrow = x + (size_t)(nb + m) * 8;
    float xv[8];
#pragma unroll
    for (int f = 0; f < 8; ++f) xv[f] = xrow[f];

    short8 a0, a1;
#pragma unroll
    for (int j = 0; j < 8; ++j) {
        int c0 = q * 8 + j, c1 = 32 + q * 8 + j;
        float s0 = sbt[c0], s1 = sbt[c1];
#pragma unroll
        for (int f = 0; f < 8; ++f) {
            s0 += xv[f] * sWt[f * 64 + c0];
            s1 += xv[f] * sWt[f * 64 + c1];
        }
        a0[j] = f2bs(fmaxf(s0, 0.f));
        a1[j] = f2bs(fmaxf(s1, 0.f));
    }

    int ty[4];
#pragma unroll
    for (int r = 0; r < 4; ++r) ty[r] = ntype[nb + q * 4 + r];

#pragma unroll
    for (int t = 0; t < 4; ++t) {
        const short* wp = (const short*)(WpT + (size_t)(t * 16 + m) * 64) + q * 8;
        short8 b0 = *(const short8*)(wp);
        short8 b1 = *(const short8*)(wp + 32);
        f32x4 acc = {0.f, 0.f, 0.f, 0.f};
        acc = __builtin_amdgcn_mfma_f32_16x16x32_bf16(a0, b0, acc, 0, 0, 0);
        acc = __builtin_amdgcn_mfma_f32_16x16x32_bf16(a1, b1, acc, 0, 0, 0);
        int col = t * 16 + m;
#pragma unroll
        for (int r = 0; r < 4; ++r) {
            int nd = nb + q * 4 + r;
            short vb = f2bs(acc[r] + TyB[ty[r] * 64 + col]);
            h0b[(size_t)nd * 64 + col] = *reinterpret_cast<bf16*>(&vb);
            shw[(q * 4 + r) * 72 + col] = vb;
        }
    }
    short8 ha0 = *(const short8*)(&shw[m * 72 + q * 8]);
    short8 ha1 = *(const short8*)(&shw[m * 72 + 32 + q * 8]);
#pragma unroll
    for (int t = 0; t < 12; ++t) {
        const short* wp = (const short*)(WT0 + (size_t)(t * 16 + m) * 64) + q * 8;
        short8 b0 = *(const short8*)(wp);
        short8 b1 = *(const short8*)(wp + 32);
        f32x4 acc = {0.f, 0.f, 0.f, 0.f};
        acc = __builtin_amdgcn_mfma_f32_16x16x32_bf16(ha0, b0, acc, 0, 0, 0);
        acc = __builtin_amdgcn_mfma_f32_16x16x32_bf16(ha1, b1, acc, 0, 0, 0);
        int col = t * 16 + m;
        int mat = col >> 6, c = col & 63;
        float bias = (mat == 0) ? bl0[c] : (mat == 1) ? br0[c] : bc0[c];
        bf16* dst = (mat == 0) ? xlo : (mat == 1) ? xro : reso;
#pragma unroll
        for (int r = 0; r < 4; ++r)
            dst[(size_t)(nb + q * 4 + r) * 64 + c] = f2b(acc[r] + bias);
    }
}

// ---------------- CSR scan + degree histogram (bucket = 63 - min(deg,63): LPT) ----------------
__global__ void k_scan_local(const int* __restrict__ counts, int* __restrict__ row_raw,
                             int* __restrict__ bsum, int* __restrict__ hist, int n) {
    __shared__ int part[256];
    __shared__ int lh[64];
    int tid = threadIdx.x;
    if (tid < 64) lh[tid] = 0;
    __syncthreads();
    int base = blockIdx.x * 1024 + tid * 4;
    int d0 = (base     < n) ? counts[base]     : -1;
    int d1 = (base + 1 < n) ? counts[base + 1] : -1;
    int d2 = (base + 2 < n) ? counts[base + 2] : -1;
    int d3 = (base + 3 < n) ? counts[base + 3] : -1;
    if (d0 >= 0) atomicAdd(&lh[63 - (d0 < 63 ? d0 : 63)], 1);
    if (d1 >= 0) atomicAdd(&lh[63 - (d1 < 63 ? d1 : 63)], 1);
    if (d2 >= 0) atomicAdd(&lh[63 - (d2 < 63 ? d2 : 63)], 1);
    if (d3 >= 0) atomicAdd(&lh[63 - (d3 < 63 ? d3 : 63)], 1);
    int c0 = d0 + 1, c1 = d1 + 1, c2 = d2 + 1, c3 = d3 + 1;
    part[tid] = c0 + c1 + c2 + c3;
    __syncthreads();
    for (int off = 1; off < 256; off <<= 1) {
        int t = (tid >= off) ? part[tid - off] : 0;
        __syncthreads();
        part[tid] += t;
        __syncthreads();
    }
    int ex = (tid == 0) ? 0 : part[tid - 1];
    if (base     < n) row_raw[base]     = ex;
    if (base + 1 < n) row_raw[base + 1] = ex + c0;
    if (base + 2 < n) row_raw[base + 2] = ex + c0 + c1;
    if (base + 3 < n) row_raw[base + 3] = ex + c0 + c1 + c2;
    if (tid == 255) bsum[blockIdx.x] = part[255];
    if (tid < 64 && lh[tid] > 0) atomicAdd(&hist[tid], lh[tid]);
}

__global__ void k_scan_bsum(int* __restrict__ bsum, int* __restrict__ row_ptr,
                            int* __restrict__ hist, int g, int n) {
    int lane = threadIdx.x;
    int orig = (lane < g) ? bsum[lane] : 0;
    int v = orig;
#pragma unroll
    for (int off = 1; off < 64; off <<= 1) {
        int t = __shfl_up(v, off, 64);
        if (lane >= off) v += t;
    }
    if (lane < g) bsum[lane] = v - orig;
    if (lane == 63) row_ptr[n] = v;

    int ho = hist[lane];
    int hv = ho;
#pragma unroll
    for (int off = 1; off < 64; off <<= 1) {
        int t = __shfl_up(hv, off, 64);
        if (lane >= off) hv += t;
    }
    hist[lane] = hv - ho;
}

__global__ void k_build(const int* __restrict__ src, const int* __restrict__ dst,
                        const int* __restrict__ row_raw, const int* __restrict__ bsum,
                        const int* __restrict__ rank, const int* __restrict__ counts,
                        int* __restrict__ row_ptr, int* __restrict__ csr_src,
                        int* __restrict__ hist, int* __restrict__ perm,
                        int n, int e) {
    __shared__ int lh[64];
    __shared__ int gbase[64];
    int tid = threadIdx.x;
    int i = blockIdx.x * 256 + tid;
    bool nodework = (blockIdx.x * 256) < n;
    if (nodework) {
        if (tid < 64) lh[tid] = 0;
        __syncthreads();
        int bucket = 0, myrank = -1;
        if (i < n) {
            int d = counts[i];
            bucket = 63 - (d < 63 ? d : 63);   // LPT: high degree -> low bucket
            myrank = atomicAdd(&lh[bucket], 1);
        }
        __syncthreads();
        if (tid < 64 && lh[tid] > 0) gbase[tid] = atomicAdd(&hist[tid], lh[tid]);
        __syncthreads();
        if (i < n) perm[gbase[bucket] + myrank] = i;
    }
    if (i < n) {
        int rp = row_raw[i] + bsum[i >> 10];
        row_ptr[i] = rp;
        csr_src[rp] = i;
    }
    if (i < e) {
        int d = dst[i];
        int pos = row_raw[d] + bsum[d >> 10] + 1 + rank[i];
        csr_src[pos] = src[i];
    }
}

// ---------------- GAT core (verified round-15 numerics) ----------------
#define GAT2_STEP(E_IDX, LS, A0S, A1S)                                            \
    {                                                                             \
        int s_ = csr_src[E_IDX];                                                  \
        unsigned int xu_ = *(const unsigned int*)((const unsigned short*)xl +     \
                                                  (size_t)s_ * 64 + ch);          \
        float x0_ = bflo(xu_), x1_ = bfhi(xu_);                                   \
        float t0_ = x0_ + xr0; t0_ = fmaxf(t0_, 0.2f * t0_);                      \
        float t1_ = x1_ + xr1; t1_ = fmaxf(t1_, 0.2f * t1_);                      \
        float p_ = t0_ * at0 + t1_ * at1;                                         \
        p_ += __shfl_xor(p_, 1, 64);                                              \
        p_ += __shfl_xor(p_, 2, 64);                                              \
        p_ += __shfl_xor(p_, 4, 64);                                              \
        float pe_ = __expf(fminf(p_, 60.f));                                      \
        A0S += pe_ * x0_;  A1S += pe_ * x1_;  LS += pe_;                          \
    }

// gat phase: node ids from perm; result into sh tile; ids into sid
#define GAT_PHASE_BODY                                                            \
    int tid = threadIdx.x;                                                        \
    int wave = tid >> 6, lane = tid & 63;                                         \
    int half = lane >> 5;                                                         \
    int L = lane & 31;                                                            \
    int head = L >> 3, cp = L & 7;                                                \
    int ch = head * 16 + cp * 2;                                                  \
    int nl = wave * 2 + half;                                                     \
    int idx = blockIdx.x * 16 + nl;                                               \
    bool valid = idx < n;                                                         \
    int v = valid ? perm[idx] : 0;                                                \
    if (L == 0) sid[nl] = valid ? v : -1;                                         \
    unsigned int xru = *(const unsigned int*)((const unsigned short*)xr +         \
                                              (size_t)v * 64 + ch);               \
    float xr0 = bflo(xru), xr1 = bfhi(xru);                                       \
    float at0 = att[ch], at1 = att[ch + 1];                                       \
    int beg = row_ptr[v];                                                         \
    int end = valid ? row_ptr[v + 1] : beg;                                       \
    float l0 = 0.f, A00 = 0.f, A01 = 0.f;                                         \
    float l1 = 0.f, A10 = 0.f, A11 = 0.f;                                         \
    float l2 = 0.f, A20 = 0.f, A21 = 0.f;                                         \
    float l3 = 0.f, A30 = 0.f, A31 = 0.f;                                         \
    int e = beg;                                                                  \
    for (; e + 3 < end; e += 4) {                                                 \
        GAT2_STEP(e,     l0, A00, A01)                                            \
        GAT2_STEP(e + 1, l1, A10, A11)                                            \
        GAT2_STEP(e + 2, l2, A20, A21)                                            \
        GAT2_STEP(e + 3, l3, A30, A31)                                            \
    }                                                                             \
    int rem = end - e;                                                            \
    if (rem > 0) GAT2_STEP(e,     l0, A00, A01)                                   \
    if (rem > 1) GAT2_STEP(e + 1, l1, A10, A11)                                   \
    if (rem > 2) GAT2_STEP(e + 2, l2, A20, A21)                                   \
    float lsum = (l0 + l1) + (l2 + l3);                                           \
    float inv = 1.f / (lsum + 1e-16f);                                            \
    float acc0 = ((A00 + A10) + (A20 + A30)) * inv;                               \
    float acc1 = ((A01 + A11) + (A21 + A31)) * inv;                               \
    unsigned int ru = *(const unsigned int*)((const unsigned short*)res +         \
                                             (size_t)v * 64 + ch);                \
    unsigned int hu = *(const unsigned int*)((const unsigned short*)h0b +         \
                                             (size_t)v * 64 + ch);                \
    float o0 = acc0 + bflo(ru);                                                   \
    float o1 = acc1 + bfhi(ru);                                                   \
    float a = alpha_p[0];                                                         \
    float t0 = a * o0 + (1.f - a) * bflo(hu);                                     \
    float t1 = a * o1 + (1.f - a) * bfhi(hu);                                     \
    float mu = t0 + t1;                                                           \
    _Pragma("unroll")                                                             \
    for (int o = 1; o < 32; o <<= 1) mu += __shfl_xor(mu, o, 64);                 \
    mu *= (1.f / 64.f);                                                           \
    float d0 = t0 - mu, d1 = t1 - mu;                                             \
    float var = d0 * d0 + d1 * d1;                                                \
    _Pragma("unroll")                                                             \
    for (int o = 1; o < 32; o <<= 1) var += __shfl_xor(var, o, 64);               \
    var *= (1.f / 64.f);                                                          \
    float rs = rsqrtf(var + 1e-5f);                                               \
    float hn0 = gamma[ch] * d0 * rs + beta[ch];                                   \
    float hn1 = gamma[ch + 1] * d1 * rs + beta[ch + 1];                           \
    *(unsigned int*)((char*)sh + nl * 144 + ch * 2) = packbf(hn0, hn1);           \
    __syncthreads();

// ---------------- gat + next-layer xform fused (16 perm-nodes/block, 512 threads) ----------------
__global__ __launch_bounds__(512) void k_gatx(
        const bf16* __restrict__ xl, const bf16* __restrict__ xr,
        const bf16* __restrict__ res, const bf16* __restrict__ h0b,
        const float* __restrict__ att, const float* __restrict__ gamma,
        const float* __restrict__ beta, const float* __restrict__ alpha_p,
        const int* __restrict__ row_ptr, const int* __restrict__ csr_src,
        const int* __restrict__ perm,
        const bf16* __restrict__ WTn, const float* __restrict__ bln,
        const float* __restrict__ brn, const float* __restrict__ bcn,
        bf16* __restrict__ xlo, bf16* __restrict__ xro, bf16* __restrict__ reso,
        int n) {
    __shared__ __align__(16) short sh[16 * 72];
    __shared__ int sid[16];
    GAT_PHASE_BODY

    int m = lane & 15, q = lane >> 4;
    short8 ha0 = *(const short8*)(&sh[m * 72 + q * 8]);
    short8 ha1 = *(const short8*)(&sh[m * 72 + 32 + q * 8]);
    for (int t = wave; t < 12; t += 8) {
        const short* wp = (const short*)(WTn + (size_t)(t * 16 + m) * 64) + q * 8;
        short8 b0 = *(const short8*)(wp);
        short8 b1 = *(const short8*)(wp + 32);
        f32x4 acc = {0.f, 0.f, 0.f, 0.f};
        acc = __builtin_amdgcn_mfma_f32_16x16x32_bf16(ha0, b0, acc, 0, 0, 0);
        acc = __builtin_amdgcn_mfma_f32_16x16x32_bf16(ha1, b1, acc, 0, 0, 0);
        int col = t * 16 + m;
        int mat = col >> 6, c = col & 63;
        float bias = (mat == 0) ? bln[c] : (mat == 1) ? brn[c] : bcn[c];
        bf16* dst = (mat == 0) ? xlo : (mat == 1) ? xro : reso;
#pragma unroll
        for (int r = 0; r < 4; ++r) {
            int nd = sid[q * 4 + r];
            if (nd >= 0) dst[(size_t)nd * 64 + c] = f2b(acc[r] + bias);
        }
    }
}

// ---------------- last gat + output head fused ----------------
__global__ __launch_bounds__(512) void k_gath(
        const bf16* __restrict__ xl, const bf16* __restrict__ xr,
        const bf16* __restrict__ res, const bf16* __restrict__ h0b,
        const float* __restrict__ att, const float* __restrict__ gamma,
        const float* __restrict__ beta, const float* __restrict__ alpha_p,
        const int* __restrict__ row_ptr, const int* __restrict__ csr_src,
        const int* __restrict__ perm,
        const bf16* __restrict__ W1T, const float* __restrict__ b1,
        const float* __restrict__ W2, const float* __restrict__ b2,
        float* __restrict__ out, int n) {
    __shared__ __align__(16) short sh[16 * 72];
    __shared__ int sid[16];
    GAT_PHASE_BODY

    if (wave == 0) {
        int m = lane & 15, q = lane >> 4;
        short8 ha0 = *(const short8*)(&sh[m * 72 + q * 8]);
        short8 ha1 = *(const short8*)(&sh[m * 72 + 32 + q * 8]);

        const short* w0p = (const short*)(W1T + (size_t)m * 64) + q * 8;
        const short* w1p = (const short*)(W1T + (size_t)(16 + m) * 64) + q * 8;
        short8 b00 = *(const short8*)(w0p);
        short8 b01 = *(const short8*)(w0p + 32);
        short8 b10 = *(const short8*)(w1p);
        short8 b11 = *(const short8*)(w1p + 32);

        f32x4 acc0 = {0.f, 0.f, 0.f, 0.f};
        f32x4 acc1 = {0.f, 0.f, 0.f, 0.f};
        acc0 = __builtin_amdgcn_mfma_f32_16x16x32_bf16(ha0, b00, acc0, 0, 0, 0);
        acc0 = __builtin_amdgcn_mfma_f32_16x16x32_bf16(ha1, b01, acc0, 0, 0, 0);
        acc1 = __builtin_amdgcn_mfma_f32_16x16x32_bf16(ha0, b10, acc1, 0, 0, 0);
        acc1 = __builtin_amdgcn_mfma_f32_16x16x32_bf16(ha1, b11, acc1, 0, 0, 0);

        float w2a = W2[m], w2b = W2[16 + m];
        float bb0 = b1[m], bb1 = b1[16 + m];
        float part[4];
#pragma unroll
        for (int r = 0; r < 4; ++r)
            part[r] = fmaxf(acc0[r] + bb0, 0.f) * w2a + fmaxf(acc1[r] + bb1, 0.f) * w2b;
#pragma unroll
        for (int mask = 1; mask < 16; mask <<= 1) {
#pragma unroll
            for (int r = 0; r < 4; ++r) part[r] += __shfl_xor(part[r], mask, 64);
        }
        if (m == 0) {
            float bb2 = b2[0];
#pragma unroll
            for (int r = 0; r < 4; ++r) {
                int nd = sid[q * 4 + r];
                if (nd >= 0) out[nd] = 1.f / (1.f + __expf(-(part[r] + bb2)));
            }
        }
    }
}

extern "C" void kernel_launch(void* const* d_in, const int* in_sizes, int n_in,
                              void* d_out, int out_size, void* d_ws, size_t ws_size,
                              hipStream_t stream) {
    const float* x     = (const float*)d_in[0];
    const int*   ntype = (const int*)d_in[1];
    const int*   esrc  = (const int*)d_in[2];
    const int*   edst  = (const int*)d_in[3];
    const float* Wt    = (const float*)d_in[4];
    const float* bt    = (const float*)d_in[5];
    const float* Et    = (const float*)d_in[6];
    const float* Wp    = (const float*)d_in[7];
    const float* bp    = (const float*)d_in[8];
    const float* Wl    = (const float*)d_in[9];
    const float* bl    = (const float*)d_in[10];
    const float* Wr    = (const float*)d_in[11];
    const float* br    = (const float*)d_in[12];
    const float* att   = (const float*)d_in[13];
    const float* Wres  = (const float*)d_in[14];
    const float* bconv = (const float*)d_in[15];
    const float* gamma = (const float*)d_in[16];
    const float* beta  = (const float*)d_in[17];
    const float* alpha = (const float*)d_in[18];
    const float* W1    = (const float*)d_in[19];
    const float* b1    = (const float*)d_in[20];
    const float* W2    = (const float*)d_in[21];
    const float* b2    = (const float*)d_in[22];
    float* out = (float*)d_out;

    const int N = in_sizes[1];   // 50000
    const int E = in_sizes[2];   // 800000

    const int G = (N + 1023) / 1024;

    size_t need = 256
                + (size_t)N * 64 * 2 * 7
                + (size_t)36864 * 2 + (size_t)4096 * 2 + (size_t)2048 * 2
                + (size_t)192 * 4
                + (size_t)N * 4
                + (size_t)(N + 1) * 4
                + (size_t)(N + 64) * 4
                + (size_t)N * 4
                + (size_t)E * 4
                + 256
                + (size_t)(E + N) * 4;

    if (ws_size < need) {
        k_sentinel<<<(N + 255) / 256, 256, 0, stream>>>(out, N,
                                                        100.0f + (float)(ws_size >> 20));
        return;
    }

    char* ws = (char*)d_ws;
    ws += 256;
    bf16* h0b   = (bf16*)ws;  ws += (size_t)N * 64 * 2;
    bf16* xlA   = (bf16*)ws;  ws += (size_t)N * 64 * 2;
    bf16* xrA   = (bf16*)ws;  ws += (size_t)N * 64 * 2;
    bf16* resA  = (bf16*)ws;  ws += (size_t)N * 64 * 2;
    bf16* xlB   = (bf16*)ws;  ws += (size_t)N * 64 * 2;
    bf16* xrB   = (bf16*)ws;  ws += (size_t)N * 64 * 2;
    bf16* resB  = (bf16*)ws;  ws += (size_t)N * 64 * 2;
    bf16* WT    = (bf16*)ws;  ws += (size_t)36864 * 2;
    bf16* WpT   = (bf16*)ws;  ws += (size_t)4096 * 2;
    bf16* W1T   = (bf16*)ws;  ws += (size_t)2048 * 2;
    float* TyB  = (float*)ws; ws += (size_t)192 * 4;
    int* row_raw = (int*)ws;  ws += (size_t)N * 4;
    int* row_ptr = (int*)ws;  ws += (size_t)(N + 1) * 4;
    int* counts  = (int*)ws;  ws += (size_t)N * 4;
    int* hist    = (int*)ws;  ws += (size_t)64 * 4;
    int* perm    = (int*)ws;  ws += (size_t)N * 4;
    int* rank    = (int*)ws;  ws += (size_t)E * 4;
    int* bsum    = (int*)ws;  ws += 256;
    int* csr_src = (int*)ws;  ws += (size_t)(E + N) * 4;

    hipMemsetAsync(counts, 0, (size_t)(N + 64) * 4, stream);
    k_setup<<<PREP_BLOCKS + (E + 255) / 256, 256, 0, stream>>>(
        Wl, Wr, Wres, Wp, W1, Et, bp, WT, WpT, W1T, TyB, edst, counts, rank, E);
    k_encx<<<(N + 63) / 64, 256, 0, stream>>>(x, ntype, Wt, bt, WpT, TyB, h0b,
                                              WT, bl, br, bconv, xlA, xrA, resA, N);
    k_scan_local<<<G, 256, 0, stream>>>(counts, row_raw, bsum, hist, N);
    k_scan_bsum<<<1, 64, 0, stream>>>(bsum, row_ptr, hist, G, N);
    k_build<<<(E + 255) / 256, 256, 0, stream>>>(esrc, edst, row_raw, bsum, rank,
                                                 counts, row_ptr, csr_src, hist, perm,
                                                 N, E);

    k_gatx<<<(N + 15) / 16, 512, 0, stream>>>(
        xlA, xrA, resA, h0b, att, gamma, beta, alpha, row_ptr, csr_src, perm,
        WT + 12288, bl + 64, br + 64, bconv + 64, xlB, xrB, resB, N);
    k_gatx<<<(N + 15) / 16, 512, 0, stream>>>(
        xlB, xrB, resB, h0b, att + 64, gamma + 64, beta + 64, alpha, row_ptr, csr_src,
        perm, WT + 24576, bl + 128, br + 128, bconv + 128, xlA, xrA, resA, N);
    k_gath<<<(N + 15) / 16, 512, 0, stream>>>(
        xlA, xrA, resA, h0b, att + 128, gamma + 128, beta + 128, alpha,
        row_ptr, csr_src, perm, W1T, b1, W2, b2, out, N);
}